// Round 6
// baseline (66.097 us; speedup 1.0000x reference)
//
#include <hip/hip_runtime.h>

#define CDIM 256
#define NDET 900
#define NMAP 100
#define NPTS 20
#define NBLK (NDET + NMAP)

__device__ __forceinline__ const float* lvlPtr(int l, const float* p2, const float* p3,
                                               const float* p4, const float* p5) {
    return (l == 0) ? p2 : (l == 1) ? p3 : (l == 2) ? p4 : p5;
}
__device__ __forceinline__ int lvlHW(int l) {
    return (l == 0) ? 19200 : (l == 1) ? 4800 : (l == 2) ? 1200 : 300;
}

__global__ __launch_bounds__(256) void autonav_fused(
    const float* __restrict__ p2, const float* __restrict__ p3,
    const float* __restrict__ p4, const float* __restrict__ p5,
    const float* __restrict__ Kin, const float* __restrict__ Ein,
    const float* __restrict__ det3d, const float* __restrict__ detfull,
    const float* __restrict__ mapanch,
    const float* __restrict__ W1d, const float* __restrict__ b1d,
    const float* __restrict__ Wcd, const float* __restrict__ bcd,
    const float* __restrict__ Wod, const float* __restrict__ bod,
    const float* __restrict__ W1m, const float* __restrict__ b1m,
    const float* __restrict__ Wcm, const float* __restrict__ bcm,
    const float* __restrict__ Wom, const float* __restrict__ bom,
    float* __restrict__ out)
{
    const int pt = blockIdx.x;      // 0..999: 0..899 det, 900..999 map
    const int t  = threadIdx.x;     // channel
    const bool isDet = (pt < NDET);
    const int m = pt - NDET;

    __shared__ float s_gx[6], s_gy[6];
    __shared__ int   s_valid[6];
    __shared__ float s_homo[4];
    __shared__ int   s_off[24][4];  // (cam*4+level) x corner
    __shared__ float s_w[24][4];
    __shared__ float s_vec[CDIM];
    __shared__ int   s_list[24];
    __shared__ int   s_n;

    // ---- homogeneous point ----
    if (t == 0) {
        float h0, h1, h2;
        if (isDet) {
            h0 = det3d[pt * 3 + 0];
            h1 = det3d[pt * 3 + 1];
            h2 = det3d[pt * 3 + 2];
        } else {
            float cx = 0.f, cy = 0.f;
            for (int j = 0; j < NPTS; ++j) {
                cx += mapanch[(m * NPTS + j) * 2 + 0];
                cy += mapanch[(m * NPTS + j) * 2 + 1];
            }
            h0 = cx / (float)NPTS;
            h1 = cy / (float)NPTS;
            h2 = 0.f;
        }
        s_homo[0] = h0; s_homo[1] = h1; s_homo[2] = h2; s_homo[3] = 1.f;
    }
    __syncthreads();

    // ---- projection (one thread per camera) ----
    if (t < 6) {
        const int cam = t;
        const float h0 = s_homo[0], h1 = s_homo[1], h2 = s_homo[2], h3 = s_homo[3];
        float pc[3];
        #pragma unroll
        for (int i = 0; i < 3; ++i) {
            pc[i] = Ein[cam * 16 + i * 4 + 0] * h0
                  + Ein[cam * 16 + i * 4 + 1] * h1
                  + Ein[cam * 16 + i * 4 + 2] * h2
                  + Ein[cam * 16 + i * 4 + 3] * h3;
        }
        const float q0 = Kin[cam * 9 + 0] * pc[0] + Kin[cam * 9 + 1] * pc[1] + Kin[cam * 9 + 2] * pc[2];
        const float q1 = Kin[cam * 9 + 3] * pc[0] + Kin[cam * 9 + 4] * pc[1] + Kin[cam * 9 + 5] * pc[2];
        const float q2 = Kin[cam * 9 + 6] * pc[0] + Kin[cam * 9 + 7] * pc[1] + Kin[cam * 9 + 8] * pc[2];
        const float depth = q2;
        const float u = q0 / (depth + 1e-6f);
        const float v = q1 / (depth + 1e-6f);
        s_valid[cam] = (depth > 0.1f) ? 1 : 0;
        s_gx[cam] = u / 640.0f * 2.0f - 1.0f;
        s_gy[cam] = v / 480.0f * 2.0f - 1.0f;
    }
    __syncthreads();

    // ---- per (cam, level) bilinear setup ----
    if (t < 24) {
        const int cam = t >> 2, l = t & 3;
        const int Hs[4] = {120, 60, 30, 15};
        const int Ws[4] = {160, 80, 40, 20};
        const int H = Hs[l], W = Ws[l];
        const float gx = s_gx[cam], gy = s_gy[cam];
        const float x = (gx + 1.f) * (W * 0.5f) - 0.5f;
        const float y = (gy + 1.f) * (H * 0.5f) - 0.5f;
        const float x0f = floorf(x), y0f = floorf(y);
        const float wx1 = x - x0f, wx0 = 1.f - wx1;
        const float wy1 = y - y0f, wy0 = 1.f - wy1;
        const float x1f = x0f + 1.f, y1f = y0f + 1.f;
        const bool bx0 = (x0f >= 0.f) && (x0f <= (float)(W - 1));
        const bool bx1 = (x1f >= 0.f) && (x1f <= (float)(W - 1));
        const bool by0 = (y0f >= 0.f) && (y0f <= (float)(H - 1));
        const bool by1 = (y1f >= 0.f) && (y1f <= (float)(H - 1));
        const int xc0 = (int)fminf(fmaxf(x0f, 0.f), (float)(W - 1));
        const int xc1 = (int)fminf(fmaxf(x1f, 0.f), (float)(W - 1));
        const int yc0 = (int)fminf(fmaxf(y0f, 0.f), (float)(H - 1));
        const int yc1 = (int)fminf(fmaxf(y1f, 0.f), (float)(H - 1));
        const int base = cam * CDIM * H * W;
        s_off[t][0] = base + yc0 * W + xc0;
        s_off[t][1] = base + yc0 * W + xc1;
        s_off[t][2] = base + yc1 * W + xc0;
        s_off[t][3] = base + yc1 * W + xc1;
        s_w[t][0] = (bx0 && by0) ? wx0 * wy0 : 0.f;
        s_w[t][1] = (bx1 && by0) ? wx1 * wy0 : 0.f;
        s_w[t][2] = (bx0 && by1) ? wx0 * wy1 : 0.f;
        s_w[t][3] = (bx1 && by1) ? wx1 * wy1 : 0.f;
    }
    __syncthreads();

    // ---- compact list of tiles with nonzero contribution (deterministic) ----
    if (t == 0) {
        int n = 0;
        for (int tt = 0; tt < 24; ++tt) {
            const int cam = tt >> 2;
            const float wsum = s_w[tt][0] + s_w[tt][1] + s_w[tt][2] + s_w[tt][3];
            if (s_valid[cam] && wsum != 0.f) s_list[n++] = tt;
        }
        s_n = n;
    }
    __syncthreads();

    // ---- gather: chunks of 8 tiles, 32 loads in flight, static reg indexing ----
    float acc = 0.f;
    const int n = s_n;
    for (int base = 0; base < 24; base += 8) {
        if (base >= n) break;           // block-uniform
        float v[8][4];
        #pragma unroll
        for (int j = 0; j < 8; ++j) {
            const int idx = base + j;
            if (idx < n) {              // block-uniform
                const int tt = s_list[idx];
                const int l = tt & 3;
                const float* f = lvlPtr(l, p2, p3, p4, p5);
                const int cHW = t * lvlHW(l);
                v[j][0] = f[s_off[tt][0] + cHW];
                v[j][1] = f[s_off[tt][1] + cHW];
                v[j][2] = f[s_off[tt][2] + cHW];
                v[j][3] = f[s_off[tt][3] + cHW];
            }
        }
        #pragma unroll
        for (int j = 0; j < 8; ++j) {
            const int idx = base + j;
            if (idx < n) {
                const int tt = s_list[idx];
                acc += s_w[tt][0] * v[j][0] + s_w[tt][1] * v[j][1]
                     + s_w[tt][2] * v[j][2] + s_w[tt][3] * v[j][3];
            }
        }
    }
    const float agg = (acc * 0.25f) / 6.0f;

    s_vec[t] = agg;
    __syncthreads();

    // ---- hidden layer GEMV: h = relu(agg @ W1 + b1) ----
    const float* __restrict__ W1 = isDet ? W1d : W1m;
    const float* __restrict__ b1 = isDet ? b1d : b1m;
    float hsum = b1[t];
    #pragma unroll 8
    for (int k = 0; k < CDIM; ++k) {
        hsum = fmaf(s_vec[k], W1[k * CDIM + t], hsum);
    }
    const float hval = fmaxf(hsum, 0.f);
    __syncthreads();
    s_vec[t] = hval;
    __syncthreads();

    // ---- output heads: 16 lanes per output, shfl-reduce ----
    const int g  = t >> 4;   // group 0..15
    const int ln = t & 15;   // lane within group
    const int nOut = isDet ? 15 : 43;
    #pragma unroll
    for (int rep = 0; rep < 3; ++rep) {
        const int o = g + rep * 16;
        float sp = 0.f;
        const float* Wp = nullptr;
        int stride = 0, oo = 0, ooff = 0;
        float bias = 0.f;
        const bool active = (o < nOut);
        if (active) {
            float addv = 0.f;
            if (isDet) {
                if (o < 4) { Wp = Wcd; stride = 4;  oo = o;     ooff = pt * 4 + oo;        bias = bcd[oo]; }
                else       { Wp = Wod; stride = 11; oo = o - 4; ooff = 3600 + pt * 11 + oo; bias = bod[oo];
                             addv = detfull[pt * 11 + oo]; }
            } else {
                if (o < 3) { Wp = Wcm; stride = 3;  oo = o;     ooff = 13500 + m * 3 + oo; bias = bcm[oo]; }
                else       { Wp = Wom; stride = 40; oo = o - 3; ooff = 13800 + m * 40 + oo; bias = bom[oo];
                             addv = mapanch[m * 40 + oo]; }
            }
            bias += addv;
            #pragma unroll
            for (int kk = 0; kk < 16; ++kk) {
                const int k = ln + kk * 16;
                sp = fmaf(s_vec[k], Wp[k * stride + oo], sp);
            }
        }
        // reduce across the 16-lane group (stays within the 64-lane wave)
        #pragma unroll
        for (int off = 1; off < 16; off <<= 1) {
            sp += __shfl_xor(sp, off, 64);
        }
        if (active && ln == 0) {
            out[ooff] = sp + bias;
        }
    }
}

extern "C" void kernel_launch(void* const* d_in, const int* in_sizes, int n_in,
                              void* d_out, int out_size, void* d_ws, size_t ws_size,
                              hipStream_t stream) {
    const float* p2      = (const float*)d_in[0];
    const float* p3      = (const float*)d_in[1];
    const float* p4      = (const float*)d_in[2];
    const float* p5      = (const float*)d_in[3];
    const float* Kin     = (const float*)d_in[4];
    const float* Ein     = (const float*)d_in[5];
    const float* det3d   = (const float*)d_in[6];
    const float* detfull = (const float*)d_in[7];
    const float* mapanch = (const float*)d_in[8];
    const float* W1d     = (const float*)d_in[9];
    const float* b1d     = (const float*)d_in[10];
    const float* Wcd     = (const float*)d_in[11];
    const float* bcd     = (const float*)d_in[12];
    const float* Wod     = (const float*)d_in[13];
    const float* bod     = (const float*)d_in[14];
    const float* W1m     = (const float*)d_in[15];
    const float* b1m     = (const float*)d_in[16];
    const float* Wcm     = (const float*)d_in[17];
    const float* bcm     = (const float*)d_in[18];
    const float* Wom     = (const float*)d_in[19];
    const float* bom     = (const float*)d_in[20];
    float* out = (float*)d_out;

    autonav_fused<<<NBLK, 256, 0, stream>>>(
        p2, p3, p4, p5, Kin, Ein, det3d, detfull, mapanch,
        W1d, b1d, Wcd, bcd, Wod, bod, W1m, b1m, Wcm, bcm, Wom, bom, out);
}

// Round 7
// 55.323 us; speedup vs baseline: 1.1948x; 1.1948x over previous
//
#include <hip/hip_runtime.h>

#define CDIM 256
#define NDET 900
#define NMAP 100
#define NPTS 20
#define NBLK (NDET + NMAP)

__device__ __forceinline__ const float* lvlPtr(int l, const float* p2, const float* p3,
                                               const float* p4, const float* p5) {
    return (l == 0) ? p2 : (l == 1) ? p3 : (l == 2) ? p4 : p5;
}
__device__ __forceinline__ int lvlHW(int l) {
    return (l == 0) ? 19200 : (l == 1) ? 4800 : (l == 2) ? 1200 : 300;
}

__global__ __launch_bounds__(256) void autonav_fused(
    const float* __restrict__ p2, const float* __restrict__ p3,
    const float* __restrict__ p4, const float* __restrict__ p5,
    const float* __restrict__ Kin, const float* __restrict__ Ein,
    const float* __restrict__ det3d, const float* __restrict__ detfull,
    const float* __restrict__ mapanch,
    const float* __restrict__ W1d, const float* __restrict__ b1d,
    const float* __restrict__ Wcd, const float* __restrict__ bcd,
    const float* __restrict__ Wod, const float* __restrict__ bod,
    const float* __restrict__ W1m, const float* __restrict__ b1m,
    const float* __restrict__ Wcm, const float* __restrict__ bcm,
    const float* __restrict__ Wom, const float* __restrict__ bom,
    float* __restrict__ out)
{
    const int pt = blockIdx.x;      // 0..999: 0..899 det, 900..999 map
    const int t  = threadIdx.x;     // channel
    const bool isDet = (pt < NDET);
    const int m = pt - NDET;

    __shared__ int   s_off[25][4];  // 24 real tiles + 1 zero-weight dummy
    __shared__ float s_w[25][4];
    __shared__ int   s_list[32];    // padded compact list
    __shared__ int   s_n;           // padded count (multiple of 8)
    __shared__ float s_vec[CDIM];   // agg
    __shared__ float s_hid[CDIM];   // hidden

    // ---- single setup phase: wave 0, threads 0..24 ----
    if (t < 25) {
        // homogeneous point (computed redundantly per thread)
        float h0, h1, h2;
        if (isDet) {
            h0 = det3d[pt * 3 + 0];
            h1 = det3d[pt * 3 + 1];
            h2 = det3d[pt * 3 + 2];
        } else {
            float cx = 0.f, cy = 0.f;
            #pragma unroll
            for (int j = 0; j < NPTS; ++j) {
                cx += mapanch[(m * NPTS + j) * 2 + 0];
                cy += mapanch[(m * NPTS + j) * 2 + 1];
            }
            h0 = cx / (float)NPTS;
            h1 = cy / (float)NPTS;
            h2 = 0.f;
        }

        bool pred = false;
        if (t < 24) {
            const int cam = t >> 2, l = t & 3;
            // projection for this camera (redundant x4, L1-hit)
            float pc[3];
            #pragma unroll
            for (int i = 0; i < 3; ++i) {
                pc[i] = Ein[cam * 16 + i * 4 + 0] * h0
                      + Ein[cam * 16 + i * 4 + 1] * h1
                      + Ein[cam * 16 + i * 4 + 2] * h2
                      + Ein[cam * 16 + i * 4 + 3] * 1.f;
            }
            const float q0 = Kin[cam*9+0]*pc[0] + Kin[cam*9+1]*pc[1] + Kin[cam*9+2]*pc[2];
            const float q1 = Kin[cam*9+3]*pc[0] + Kin[cam*9+4]*pc[1] + Kin[cam*9+5]*pc[2];
            const float q2 = Kin[cam*9+6]*pc[0] + Kin[cam*9+7]*pc[1] + Kin[cam*9+8]*pc[2];
            const float depth = q2;
            const float u = q0 / (depth + 1e-6f);
            const float v = q1 / (depth + 1e-6f);
            const bool valid = (depth > 0.1f);
            const float gx = u / 640.0f * 2.0f - 1.0f;
            const float gy = v / 480.0f * 2.0f - 1.0f;

            const int Hs[4] = {120, 60, 30, 15};
            const int Ws[4] = {160, 80, 40, 20};
            const int H = Hs[l], W = Ws[l];
            const float x = (gx + 1.f) * (W * 0.5f) - 0.5f;
            const float y = (gy + 1.f) * (H * 0.5f) - 0.5f;
            const float x0f = floorf(x), y0f = floorf(y);
            const float wx1 = x - x0f, wx0 = 1.f - wx1;
            const float wy1 = y - y0f, wy0 = 1.f - wy1;
            const float x1f = x0f + 1.f, y1f = y0f + 1.f;
            const bool bx0 = (x0f >= 0.f) && (x0f <= (float)(W - 1));
            const bool bx1 = (x1f >= 0.f) && (x1f <= (float)(W - 1));
            const bool by0 = (y0f >= 0.f) && (y0f <= (float)(H - 1));
            const bool by1 = (y1f >= 0.f) && (y1f <= (float)(H - 1));
            const int xc0 = (int)fminf(fmaxf(x0f, 0.f), (float)(W - 1));
            const int xc1 = (int)fminf(fmaxf(x1f, 0.f), (float)(W - 1));
            const int yc0 = (int)fminf(fmaxf(y0f, 0.f), (float)(H - 1));
            const int yc1 = (int)fminf(fmaxf(y1f, 0.f), (float)(H - 1));
            const int base = cam * CDIM * H * W;
            s_off[t][0] = base + yc0 * W + xc0;
            s_off[t][1] = base + yc0 * W + xc1;
            s_off[t][2] = base + yc1 * W + xc0;
            s_off[t][3] = base + yc1 * W + xc1;
            const float w0 = (bx0 && by0) ? wx0 * wy0 : 0.f;
            const float w1 = (bx1 && by0) ? wx1 * wy0 : 0.f;
            const float w2 = (bx0 && by1) ? wx0 * wy1 : 0.f;
            const float w3 = (bx1 && by1) ? wx1 * wy1 : 0.f;
            s_w[t][0] = w0; s_w[t][1] = w1; s_w[t][2] = w2; s_w[t][3] = w3;
            pred = valid && ((w0 + w1 + w2 + w3) != 0.f);
        } else {
            // dummy tile 24: offset 0, weight 0 (reads p2, contributes nothing)
            s_off[24][0] = 0; s_off[24][1] = 0; s_off[24][2] = 0; s_off[24][3] = 0;
            s_w[24][0] = 0.f; s_w[24][1] = 0.f; s_w[24][2] = 0.f; s_w[24][3] = 0.f;
        }

        // wave-parallel compaction + padding (all within wave 0)
        const unsigned long long mask = __ballot(pred);
        const int n = __popcll(mask);
        const int rank = __popcll(mask & ((1ull << t) - 1ull));
        if (pred) s_list[rank] = t;
        const int npad = (n + 7) & ~7;
        if (t < 8 && (n + t) < npad) s_list[n + t] = 24;
        if (t == 0) s_n = npad;
    }
    __syncthreads();

    // ---- gather: branch-free chunks of 8 tiles (32 loads batched) ----
    float acc = 0.f;
    const int npad = s_n;
    for (int base = 0; base < npad; base += 8) {
        float v[8][4];
        #pragma unroll
        for (int j = 0; j < 8; ++j) {
            const int tt = s_list[base + j];
            const int l = tt & 3;
            const float* f = lvlPtr(l, p2, p3, p4, p5);
            const int cHW = t * lvlHW(l);
            v[j][0] = f[s_off[tt][0] + cHW];
            v[j][1] = f[s_off[tt][1] + cHW];
            v[j][2] = f[s_off[tt][2] + cHW];
            v[j][3] = f[s_off[tt][3] + cHW];
        }
        #pragma unroll
        for (int j = 0; j < 8; ++j) {
            const int tt = s_list[base + j];
            acc += s_w[tt][0] * v[j][0] + s_w[tt][1] * v[j][1]
                 + s_w[tt][2] * v[j][2] + s_w[tt][3] * v[j][3];
        }
    }
    const float agg = (acc * 0.25f) / 6.0f;

    s_vec[t] = agg;
    __syncthreads();

    // ---- hidden GEMV: batched 32-wide loads, 8 latency batches ----
    const float* __restrict__ W1 = isDet ? W1d : W1m;
    const float* __restrict__ b1 = isDet ? b1d : b1m;
    float hsum = b1[t];
    for (int k0 = 0; k0 < CDIM; k0 += 32) {
        float wv[32], xv[32];
        #pragma unroll
        for (int i = 0; i < 32; ++i) wv[i] = W1[(k0 + i) * CDIM + t];
        #pragma unroll
        for (int i = 0; i < 32; ++i) xv[i] = s_vec[k0 + i];
        #pragma unroll
        for (int i = 0; i < 32; ++i) hsum = fmaf(xv[i], wv[i], hsum);
    }
    s_hid[t] = fmaxf(hsum, 0.f);
    __syncthreads();

    // ---- output heads: 16 lanes per output, batched loads + shfl reduce ----
    const int g  = t >> 4;   // group 0..15
    const int ln = t & 15;   // lane in group
    const int nOut = isDet ? 15 : 43;
    const int nrep = isDet ? 1 : 3;
    for (int rep = 0; rep < nrep; ++rep) {
        const int o = g + rep * 16;
        if (o < nOut) {      // uniform across the 16-lane group
            const float* Wp; int stride, oo, ooff; float bias;
            if (isDet) {
                if (o < 4) { Wp = Wcd; stride = 4;  oo = o;     ooff = pt * 4 + oo;         bias = bcd[oo]; }
                else       { Wp = Wod; stride = 11; oo = o - 4; ooff = 3600 + pt * 11 + oo; bias = bod[oo] + detfull[pt * 11 + oo]; }
            } else {
                if (o < 3) { Wp = Wcm; stride = 3;  oo = o;     ooff = 13500 + m * 3 + oo;  bias = bcm[oo]; }
                else       { Wp = Wom; stride = 40; oo = o - 3; ooff = 13800 + m * 40 + oo; bias = bom[oo] + mapanch[m * 40 + oo]; }
            }
            float wv[16], xv[16];
            #pragma unroll
            for (int kk = 0; kk < 16; ++kk) wv[kk] = Wp[(ln + kk * 16) * stride + oo];
            #pragma unroll
            for (int kk = 0; kk < 16; ++kk) xv[kk] = s_hid[ln + kk * 16];
            float sp = 0.f;
            #pragma unroll
            for (int kk = 0; kk < 16; ++kk) sp = fmaf(xv[kk], wv[kk], sp);
            #pragma unroll
            for (int off = 1; off < 16; off <<= 1) sp += __shfl_xor(sp, off, 64);
            if (ln == 0) out[ooff] = sp + bias;
        }
    }
}

extern "C" void kernel_launch(void* const* d_in, const int* in_sizes, int n_in,
                              void* d_out, int out_size, void* d_ws, size_t ws_size,
                              hipStream_t stream) {
    const float* p2      = (const float*)d_in[0];
    const float* p3      = (const float*)d_in[1];
    const float* p4      = (const float*)d_in[2];
    const float* p5      = (const float*)d_in[3];
    const float* Kin     = (const float*)d_in[4];
    const float* Ein     = (const float*)d_in[5];
    const float* det3d   = (const float*)d_in[6];
    const float* detfull = (const float*)d_in[7];
    const float* mapanch = (const float*)d_in[8];
    const float* W1d     = (const float*)d_in[9];
    const float* b1d     = (const float*)d_in[10];
    const float* Wcd     = (const float*)d_in[11];
    const float* bcd     = (const float*)d_in[12];
    const float* Wod     = (const float*)d_in[13];
    const float* bod     = (const float*)d_in[14];
    const float* W1m     = (const float*)d_in[15];
    const float* b1m     = (const float*)d_in[16];
    const float* Wcm     = (const float*)d_in[17];
    const float* bcm     = (const float*)d_in[18];
    const float* Wom     = (const float*)d_in[19];
    const float* bom     = (const float*)d_in[20];
    float* out = (float*)d_out;

    autonav_fused<<<NBLK, 256, 0, stream>>>(
        p2, p3, p4, p5, Kin, Ein, det3d, detfull, mapanch,
        W1d, b1d, Wcd, bcd, Wod, bod, W1m, b1m, Wcm, bcm, Wom, bom, out);
}